// Round 14
// baseline (346.561 us; speedup 1.0000x reference)
//
#include <hip/hip_runtime.h>

typedef unsigned short u16;
typedef unsigned int u32;
typedef __attribute__((ext_vector_type(8))) short bf16x8;
typedef __attribute__((ext_vector_type(4))) float f32x4;

#define LCONST __launch_bounds__(256)

__device__ __forceinline__ u16 f2bf(float f) {
  u32 u = __float_as_uint(f);
  u32 r = (u + 0x7FFFu + ((u >> 16) & 1u)) >> 16;
  return (u16)r;
}
__device__ __forceinline__ float bflo(u32 w) { return __uint_as_float(w << 16); }
__device__ __forceinline__ float bfhi(u32 w) { return __uint_as_float(w & 0xFFFF0000u); }
__device__ __forceinline__ float b2f(u16 v) { return __uint_as_float(((u32)v) << 16); }

__device__ __forceinline__ float dot8(uint4 u, const float* q) {
  return q[0]*bflo(u.x) + q[1]*bfhi(u.x) + q[2]*bflo(u.y) + q[3]*bfhi(u.y)
       + q[4]*bflo(u.z) + q[5]*bfhi(u.z) + q[6]*bflo(u.w) + q[7]*bfhi(u.w);
}
__device__ __forceinline__ void fma8(uint4 u, float wt, float* a) {
  a[0] = fmaf(wt, bflo(u.x), a[0]); a[1] = fmaf(wt, bfhi(u.x), a[1]);
  a[2] = fmaf(wt, bflo(u.y), a[2]); a[3] = fmaf(wt, bfhi(u.y), a[3]);
  a[4] = fmaf(wt, bflo(u.z), a[4]); a[5] = fmaf(wt, bfhi(u.z), a[5]);
  a[6] = fmaf(wt, bflo(u.w), a[6]); a[7] = fmaf(wt, bfhi(u.w), a[7]);
}

// async global -> LDS, 16 bytes per lane. LDS dest = wave-uniform base + lane*16.
__device__ __forceinline__ void gload16(const u16* g, u16* l) {
  __builtin_amdgcn_global_load_lds(
      (const __attribute__((address_space(1))) unsigned int*)g,
      (__attribute__((address_space(3))) unsigned int*)l, 16, 0, 0);
}

// ---------------- prep: all weight transpose-casts + e-mean (one launch) ---
__global__ LCONST void prep_kernel(const float* __restrict__ e,
                                   const float* __restrict__ Wq, const float* __restrict__ Wk,
                                   const float* __restrict__ Wv, const float* __restrict__ Wo,
                                   const float* __restrict__ W1, const float* __restrict__ W2,
                                   u16* __restrict__ Wqkv_t, u16* __restrict__ Wo_t,
                                   u16* __restrict__ W1_t, u16* __restrict__ W2_t,
                                   float* __restrict__ part, u16* __restrict__ ebf) {
  int blk = blockIdx.x;
  int tid = threadIdx.x;
  if (blk < 3072) {                               // weight transpose-casts
    int idx = blk * 256 + tid;                    // 786432 total
    if (idx < 196608) {                           // Wq|Wk|Wv (256x256 each)
      int sub = idx >> 16, r = idx & 65535;
      int n = r >> 8, k = r & 255;
      const float* src = (sub == 0) ? Wq : ((sub == 1) ? Wk : Wv);
      Wqkv_t[idx] = f2bf(src[(size_t)k * 256 + n]);
    } else if (idx < 262144) {                    // Wo (256x256)
      int r = idx - 196608;
      int n = r >> 8, k = r & 255;
      Wo_t[r] = f2bf(Wo[(size_t)k * 256 + n]);
    } else if (idx < 524288) {                    // W1 (256x1024) -> [1024][256]
      int r = idx - 262144;
      int n = r >> 8, k = r & 255;
      W1_t[r] = f2bf(W1[(size_t)k * 1024 + n]);
    } else {                                      // W2 (1024x256) -> [256][1024]
      int r = idx - 524288;
      int n = r >> 10, k = r & 1023;
      W2_t[r] = f2bf(W2[(size_t)k * 256 + n]);
    }
  } else {                                        // partial mean + e->bf16
    int mb = blk - 3072;                          // 512 blocks
    int b = mb >> 5, c = mb & 31;
    size_t base = ((size_t)b * 2048 + (size_t)c * 64) * 256 + tid;
    float s = 0.f;
    #pragma unroll 8
    for (int i = 0; i < 64; i++) {
      float v = e[base + (size_t)i * 256];
      s += v;
      ebf[base + (size_t)i * 256] = f2bf(v);
    }
    part[(size_t)mb * 256 + tid] = s;
  }
}

// ---------------- GEMM core (shared by all MFMA GEMMs) ---------------------
// C = A(MxK,bf16) * Bt(NxK,bf16)^T. 512 threads, 2x4 waves.
// EPI 0: bf16 store routed into 256-wide buffers C0/C1/C2 by col>>8
// EPI 1: relu(acc+bias) -> bf16 C0 (stride N)
// EPI 4: FFN2+LN2: x=acc+bias+resbf; LN(x) -> Fout (f32)
template <int BM, int BN, int EPI>
__device__ __forceinline__ void gemm_core(
    int bid, int nwg, u16* As, u16* Bs,
    const u16* __restrict__ A, const u16* __restrict__ Bt,
    const float* __restrict__ bias,
    u16* __restrict__ C0, u16* __restrict__ C1, u16* __restrict__ C2,
    const u16* __restrict__ resbf,
    const float* __restrict__ g, const float* __restrict__ be,
    float* __restrict__ Fout, int N, int K) {
  constexpr int WR = BM / 2;                 // rows per wave
  constexpr int MR = WR / 16;                // 4 or 2
  constexpr int ACH_PW = (BM / 8) / 8;       // A 1KB chunks per wave
  constexpr int BCH_PW = 4;                  // B 1KB chunks per wave

  const int tid = threadIdx.x, lane = tid & 63, wid = tid >> 6;
  const int wm = wid >> 2, wn = wid & 3;

  const int ncol = N / BN;
  const int swz = (bid & 7) * (nwg >> 3) + (bid >> 3);
  const int mb = swz / ncol, nb = swz - mb * ncol;
  const int m0 = mb * BM, n0 = nb * BN;

  const int lrow8 = lane >> 3;               // row within 8-row chunk
  const int cg = (lane & 7) ^ lrow8;         // pre-swizzled global 16B-slot

  f32x4 acc[MR][4] = {};
  for (int kt = 0; kt < K; kt += 64) {
    #pragma unroll
    for (int it = 0; it < ACH_PW; it++) {
      int ca = wid * ACH_PW + it;
      int row = ca * 8 + lrow8;
      gload16(A + (size_t)(m0 + row) * K + kt + cg * 8, As + ca * 512);
    }
    #pragma unroll
    for (int it = 0; it < BCH_PW; it++) {
      int cb = wid * BCH_PW + it;
      int row = cb * 8 + lrow8;
      gload16(Bt + (size_t)(n0 + row) * K + kt + cg * 8, Bs + cb * 512);
    }
    __syncthreads();
    const int lr = lane & 15, hi = lane >> 4;
    #pragma unroll
    for (int kk = 0; kk < 2; kk++) {
      const int slot = (kk * 4 + hi) ^ (lr & 7);
      bf16x8 af[MR], bfr[4];
      #pragma unroll
      for (int m = 0; m < MR; m++)
        af[m] = *(const bf16x8*)&As[(wm * WR + m * 16 + lr) * 64 + slot * 8];
      #pragma unroll
      for (int n = 0; n < 4; n++)
        bfr[n] = *(const bf16x8*)&Bs[(wn * 64 + n * 16 + lr) * 64 + slot * 8];
      #pragma unroll
      for (int m = 0; m < MR; m++)
        #pragma unroll
        for (int n = 0; n < 4; n++)
          acc[m][n] = __builtin_amdgcn_mfma_f32_16x16x32_bf16(af[m], bfr[n], acc[m][n], 0, 0, 0);
    }
    __syncthreads();
  }

  const int lr = lane & 15, hi = lane >> 4;
  if constexpr (EPI == 0) {
    const int bsel = n0 >> 8;
    u16* C = (bsel == 0) ? C0 : ((bsel == 1) ? C1 : C2);
    #pragma unroll
    for (int m = 0; m < MR; m++)
      #pragma unroll
      for (int n = 0; n < 4; n++)
        #pragma unroll
        for (int r = 0; r < 4; r++) {
          int row = m0 + wm * WR + m * 16 + hi * 4 + r;
          int col = wn * 64 + n * 16 + lr;
          C[(size_t)row * 256 + col] = f2bf(acc[m][n][r]);
        }
  } else if constexpr (EPI == 1) {
    #pragma unroll
    for (int m = 0; m < MR; m++)
      #pragma unroll
      for (int n = 0; n < 4; n++)
        #pragma unroll
        for (int r = 0; r < 4; r++) {
          int row = m0 + wm * WR + m * 16 + hi * 4 + r;
          int col = n0 + wn * 64 + n * 16 + lr;
          float v = fmaxf(acc[m][n][r] + bias[col], 0.f);
          C0[(size_t)row * N + col] = f2bf(v);
        }
  } else {  // EPI 4: FFN2 + LN2 epilogue (BN=256 full rows)
    __shared__ float rs_[BM], rq_[BM];
    if (tid < BM) { rs_[tid] = 0.f; rq_[tid] = 0.f; }
    __syncthreads();
    #pragma unroll
    for (int m = 0; m < MR; m++)
      #pragma unroll
      for (int n = 0; n < 4; n++)
        #pragma unroll
        for (int r = 0; r < 4; r++) {
          int rl = wm * WR + m * 16 + hi * 4 + r;
          int col = wn * 64 + n * 16 + lr;
          size_t gi = (size_t)(m0 + rl) * 256 + col;
          acc[m][n][r] = acc[m][n][r] + bias[col] + b2f(resbf[gi]);
        }
    #pragma unroll
    for (int m = 0; m < MR; m++)
      #pragma unroll
      for (int r = 0; r < 4; r++) {
        float s = 0.f, q = 0.f;
        #pragma unroll
        for (int n = 0; n < 4; n++) { float x = acc[m][n][r]; s += x; q += x * x; }
        #pragma unroll
        for (int off = 1; off < 16; off <<= 1) {
          s += __shfl_xor(s, off);
          q += __shfl_xor(q, off);
        }
        if (lr == 0) {
          int rl = wm * WR + m * 16 + hi * 4 + r;
          atomicAdd(&rs_[rl], s);
          atomicAdd(&rq_[rl], q);
        }
      }
    __syncthreads();
    #pragma unroll
    for (int m = 0; m < MR; m++)
      #pragma unroll
      for (int n = 0; n < 4; n++)
        #pragma unroll
        for (int r = 0; r < 4; r++) {
          int rl = wm * WR + m * 16 + hi * 4 + r;
          int col = wn * 64 + n * 16 + lr;
          size_t gi = (size_t)(m0 + rl) * 256 + col;
          float mu = rs_[rl] * (1.f / 256.f);
          float var = rq_[rl] * (1.f / 256.f) - mu * mu;
          float rstd = rsqrtf(fmaxf(var, 0.f) + 1e-6f);
          Fout[gi] = g[col] * (acc[m][n][r] - mu) * rstd + be[col];
        }
  }
}

// ---------------- standalone GEMM wrapper ----------------------------------
template <int BM, int BN, int EPI>
__global__ __launch_bounds__(512, 4)
void gemm3_kernel(const u16* __restrict__ A, const u16* __restrict__ Bt,
                  const float* __restrict__ bias,
                  u16* __restrict__ C0, u16* __restrict__ C1, u16* __restrict__ C2,
                  const u16* __restrict__ resbf,
                  const float* __restrict__ g, const float* __restrict__ be,
                  float* __restrict__ Fout,
                  int M, int N, int K) {
  __shared__ __align__(16) u16 As[BM * 64];
  __shared__ __align__(16) u16 Bs[BN * 64];
  gemm_core<BM, BN, EPI>(blockIdx.x, gridDim.x, As, Bs, A, Bt, bias,
                         C0, C1, C2, resbf, g, be, Fout, N, K);
  (void)M;
}

// ---------------- MHA2 partial: 4 key-chunks per (b,h), 256 thr ------------
// partial[blk*36]: [0]=m, [1]=l, [2..33]=acc
__global__ LCONST void mha2a_kernel(const float* __restrict__ sqp, const float* __restrict__ skp,
                                    const float* __restrict__ svp, const u16* __restrict__ pk,
                                    const u16* __restrict__ pv, float* __restrict__ partial) {
  __shared__ float rmax[4], rsm[4], racc[4][32];
  const int blk = blockIdx.x;                 // bh*4 + c
  const int bh = blk >> 2, c = blk & 3;
  const int b = bh >> 3, h = bh & 7;
  const int tid = threadIdx.x;
  const int lane = tid & 63, wid = tid >> 6;
  const int off = h * 32;
  const float sc = 0.17677669529663687f;

  float qf[32];
  {
    const float* q = sqp + b * 256 + off;
    #pragma unroll
    for (int j = 0; j < 32; j++) qf[j] = q[j];
  }
  const int k0 = c * 512 + tid;               // two h-keys per thread
  const int k1 = k0 + 256;
  const u16* kp0 = pk + ((size_t)b * 2048 + k0) * 256 + off;
  const u16* kp1 = pk + ((size_t)b * 2048 + k1) * 256 + off;
  float d0 = 0.f, d1 = 0.f;
  #pragma unroll
  for (int cc = 0; cc < 4; cc++) {
    d0 += dot8(*(const uint4*)(kp0 + cc * 8), qf + cc * 8);
    d1 += dot8(*(const uint4*)(kp1 + cc * 8), qf + cc * 8);
  }
  d0 *= sc; d1 *= sc;
  float ds = -1e30f;
  if (c == 0 && tid == 0) {                   // the s-key
    float dv = 0.f;
    const float* k = skp + b * 256 + off;
    #pragma unroll
    for (int j = 0; j < 32; j++) dv = fmaf(qf[j], k[j], dv);
    ds = dv * sc;
  }
  float lmax = fmaxf(fmaxf(d0, d1), ds);
  #pragma unroll
  for (int o = 32; o; o >>= 1) lmax = fmaxf(lmax, __shfl_down(lmax, o));
  if (lane == 0) rmax[wid] = lmax;
  __syncthreads();
  const float M = fmaxf(fmaxf(rmax[0], rmax[1]), fmaxf(rmax[2], rmax[3]));

  float w0 = __expf(d0 - M), w1 = __expf(d1 - M);
  float lsum = w0 + w1;
  float a[32];
  #pragma unroll
  for (int j = 0; j < 32; j++) a[j] = 0.f;
  const u16* vp0 = pv + ((size_t)b * 2048 + k0) * 256 + off;
  const u16* vp1 = pv + ((size_t)b * 2048 + k1) * 256 + off;
  #pragma unroll
  for (int cc = 0; cc < 4; cc++) {
    fma8(*(const uint4*)(vp0 + cc * 8), w0, a + cc * 8);
    fma8(*(const uint4*)(vp1 + cc * 8), w1, a + cc * 8);
  }
  if (c == 0 && tid == 0) {
    float ws = __expf(ds - M);
    lsum += ws;
    const float* v = svp + b * 256 + off;
    #pragma unroll
    for (int j = 0; j < 32; j++) a[j] = fmaf(ws, v[j], a[j]);
  }
  #pragma unroll
  for (int o = 32; o; o >>= 1) lsum += __shfl_down(lsum, o);
  if (lane == 0) rsm[wid] = lsum;
  #pragma unroll
  for (int j = 0; j < 32; j++) {
    float v = a[j];
    #pragma unroll
    for (int o = 32; o; o >>= 1) v += __shfl_down(v, o);
    if (lane == 0) racc[wid][j] = v;
  }
  __syncthreads();
  float* P = partial + (size_t)blk * 36;
  if (tid < 32) {
    P[2 + tid] = racc[0][tid] + racc[1][tid] + racc[2][tid] + racc[3][tid];
    if (tid == 0) {
      P[0] = M;
      P[1] = rsm[0] + rsm[1] + rsm[2] + rsm[3];
    }
  }
}

// ---- fused attn1 + Wo GEMM, register-staged A (40.5 KB LDS, 3 blk/CU) -----
// Phase 1: thread (arow=tid>>3, ah=tid&7) computes 5-key attention, keeps the
// 32 bf16 outputs in 16 u32 regs. Phase 2: per k-tile, the 2 owning heads
// ds_write As[64][64] (8 KB); B staged per k-tile (32 KB).
// EPI 1: hbuf = relu(acc+bo) -> C0
// EPI 2: h2 = relu(acc+bo) -> C0; out1 = LN1(resbf + h2) -> C1
template <int EPI>
__global__ __launch_bounds__(512, 6)
void attnwo_kernel(const u16* __restrict__ hq, const u16* __restrict__ pk,
                   const u16* __restrict__ pv, const u16* __restrict__ ek,
                   const u16* __restrict__ ev, const float* __restrict__ skp,
                   const float* __restrict__ svp,
                   const u16* __restrict__ Wo_t, const float* __restrict__ bo,
                   u16* __restrict__ C0, u16* __restrict__ C1,
                   const u16* __restrict__ resbf,
                   const float* __restrict__ g, const float* __restrict__ be) {
  __shared__ __align__(16) u16 As[64 * 64];     // 8 KB, one k-tile of A
  __shared__ __align__(16) u16 Bs[256 * 64];    // 32 KB, one k-tile of B
  const int tid = threadIdx.x, lane = tid & 63, wid = tid >> 6;
  const int wm = wid >> 2, wn = wid & 3;
  const int nwg = gridDim.x, bid = blockIdx.x;
  const int swz = (bid & 7) * (nwg >> 3) + (bid >> 3);
  const int m0 = swz * 64;
  const int lrow8 = lane >> 3;
  const int cg = (lane & 7) ^ lrow8;
  const int arow = tid >> 3, ah = tid & 7;

  // prefetch Wo k-tile 0 (latency hides under the attention phase)
  #pragma unroll
  for (int it = 0; it < 4; it++) {
    int cb = wid * 4 + it;
    int row = cb * 8 + lrow8;
    gload16(Wo_t + (size_t)row * 256 + 0 * 64 + cg * 8, (u16*)Bs + cb * 512);
  }

  // ---- phase 1: per-(row,head) 5-key attention; outputs -> ov[16] regs ----
  u32 ov[16];
  {
    const size_t token = (size_t)(m0 + arow);
    const int b = (int)(token >> 11);
    const int i = (int)(token & 2047);
    const size_t tb = (size_t)b << 11;
    const size_t ip = tb + ((i + 1) & 2047);
    const size_t im = tb + ((i + 2047) & 2047);
    const int off = ah * 32;

    float qf[32];
    {
      const u16* q = hq + token * 256 + off;
      #pragma unroll
      for (int c = 0; c < 4; c++) {
        uint4 u = *(const uint4*)(q + c * 8);
        qf[c*8+0] = bflo(u.x); qf[c*8+1] = bfhi(u.x);
        qf[c*8+2] = bflo(u.y); qf[c*8+3] = bfhi(u.y);
        qf[c*8+4] = bflo(u.z); qf[c*8+5] = bfhi(u.z);
        qf[c*8+6] = bflo(u.w); qf[c*8+7] = bfhi(u.w);
      }
    }
    const u16* kr0 = pk + ip * 256 + off;
    const u16* kr1 = pk + token * 256 + off;
    const u16* kr2 = pk + im * 256 + off;
    const u16* kr3 = ek + token * 256 + off;
    float lg[5];
    {
      float d0 = 0, d1 = 0, d2 = 0, d3 = 0;
      #pragma unroll
      for (int cc = 0; cc < 4; cc++) {
        d0 += dot8(*(const uint4*)(kr0 + cc * 8), qf + cc * 8);
        d1 += dot8(*(const uint4*)(kr1 + cc * 8), qf + cc * 8);
        d2 += dot8(*(const uint4*)(kr2 + cc * 8), qf + cc * 8);
        d3 += dot8(*(const uint4*)(kr3 + cc * 8), qf + cc * 8);
      }
      lg[0] = d0; lg[1] = d1; lg[2] = d2; lg[3] = d3;
      float d4 = 0;
      const float* s = skp + b * 256 + off;
      #pragma unroll
      for (int j = 0; j < 32; j++) d4 = fmaf(qf[j], s[j], d4);
      lg[4] = d4;
    }
    const float sc = 0.17677669529663687f;      // 1/sqrt(32)
    float mx = lg[0];
    #pragma unroll
    for (int c = 1; c < 5; c++) mx = fmaxf(mx, lg[c]);
    float w[5], den = 0.f;
    #pragma unroll
    for (int c = 0; c < 5; c++) { w[c] = __expf((lg[c] - mx) * sc); den += w[c]; }

    float a[32];
    #pragma unroll
    for (int j = 0; j < 32; j++) a[j] = 0.f;
    const u16* vr0 = pv + ip * 256 + off;
    const u16* vr1 = pv + token * 256 + off;
    const u16* vr2 = pv + im * 256 + off;
    const u16* vr3 = ev + token * 256 + off;
    #pragma unroll
    for (int cc = 0; cc < 4; cc++) {
      fma8(*(const uint4*)(vr0 + cc * 8), w[0], a + cc * 8);
      fma8(*(const uint4*)(vr1 + cc * 8), w[1], a + cc * 8);
      fma8(*(const uint4*)(vr2 + cc * 8), w[2], a + cc * 8);
      fma8(*(const uint4*)(vr3 + cc * 8), w[3], a + cc * 8);
    }
    {
      const float* s = svp + b * 256 + off;
      #pragma unroll
      for (int j = 0; j < 32; j++) a[j] = fmaf(w[4], s[j], a[j]);
    }
    const float inv = 1.f / den;
    #pragma unroll
    for (int j = 0; j < 16; j++)
      ov[j] = (u32)f2bf(a[2*j] * inv) | ((u32)f2bf(a[2*j+1] * inv) << 16);
  }

  // write As for k-tile 0 (heads 0,1 own cols 0..63)
  if ((ah >> 1) == 0) {
    const int base = (ah & 1) * 4;
    #pragma unroll
    for (int c = 0; c < 4; c++) {
      int sp = (base + c) ^ (arow & 7);
      uint4 u = make_uint4(ov[c*4], ov[c*4+1], ov[c*4+2], ov[c*4+3]);
      *(uint4*)&As[arow * 64 + sp * 8] = u;
    }
  }
  __syncthreads();   // As0 ready; Bs0 drained

  // ---- phase 2: C = A @ Wo_t^T, one k-tile at a time ----
  const int lr = lane & 15, hi = lane >> 4;
  f32x4 acc[2][4] = {};
  for (int kt = 0; kt < 4; kt++) {
    #pragma unroll
    for (int kk = 0; kk < 2; kk++) {
      bf16x8 af[2], bfr[4];
      #pragma unroll
      for (int m = 0; m < 2; m++) {
        int row = wm * 32 + m * 16 + lr;
        int sp = (kk * 4 + hi) ^ (row & 7);
        af[m] = *(const bf16x8*)&As[row * 64 + sp * 8];
      }
      const int slotB = (kk * 4 + hi) ^ (lr & 7);
      #pragma unroll
      for (int n = 0; n < 4; n++)
        bfr[n] = *(const bf16x8*)&Bs[(wn * 64 + n * 16 + lr) * 64 + slotB * 8];
      #pragma unroll
      for (int m = 0; m < 2; m++)
        #pragma unroll
        for (int n = 0; n < 4; n++)
          acc[m][n] = __builtin_amdgcn_mfma_f32_16x16x32_bf16(af[m], bfr[n], acc[m][n], 0, 0, 0);
    }
    __syncthreads();
    if (kt < 3) {
      #pragma unroll
      for (int it = 0; it < 4; it++) {
        int cb = wid * 4 + it;
        int row = cb * 8 + lrow8;
        gload16(Wo_t + (size_t)row * 256 + (kt + 1) * 64 + cg * 8, (u16*)Bs + cb * 512);
      }
      if ((ah >> 1) == kt + 1) {
        const int base = (ah & 1) * 4;
        #pragma unroll
        for (int c = 0; c < 4; c++) {
          int sp = (base + c) ^ (arow & 7);
          uint4 u = make_uint4(ov[c*4], ov[c*4+1], ov[c*4+2], ov[c*4+3]);
          *(uint4*)&As[arow * 64 + sp * 8] = u;
        }
      }
      __syncthreads();
    }
  }

  if constexpr (EPI == 1) {
    #pragma unroll
    for (int m = 0; m < 2; m++)
      #pragma unroll
      for (int n = 0; n < 4; n++)
        #pragma unroll
        for (int r = 0; r < 4; r++) {
          int row = m0 + wm * 32 + m * 16 + hi * 4 + r;
          int col = wn * 64 + n * 16 + lr;
          float v = fmaxf(acc[m][n][r] + bo[col], 0.f);
          C0[(size_t)row * 256 + col] = f2bf(v);
        }
  } else {  // EPI 2: h2 + fused LN1
    __shared__ float rsum[64], rsq[64];
    if (tid < 64) { rsum[tid] = 0.f; rsq[tid] = 0.f; }
    __syncthreads();
    #pragma unroll
    for (int m = 0; m < 2; m++)
      #pragma unroll
      for (int n = 0; n < 4; n++)
        #pragma unroll
        for (int r = 0; r < 4; r++) {
          int rl = wm * 32 + m * 16 + hi * 4 + r;
          int col = wn * 64 + n * 16 + lr;
          size_t gi = (size_t)(m0 + rl) * 256 + col;
          float v = fmaxf(acc[m][n][r] + bo[col], 0.f);
          C0[gi] = f2bf(v);              // h2
          acc[m][n][r] = b2f(resbf[gi]) + v;   // e + h
        }
    #pragma unroll
    for (int m = 0; m < 2; m++)
      #pragma unroll
      for (int r = 0; r < 4; r++) {
        float s = 0.f, q = 0.f;
        #pragma unroll
        for (int n = 0; n < 4; n++) { float x = acc[m][n][r]; s += x; q += x * x; }
        #pragma unroll
        for (int off = 1; off < 16; off <<= 1) {
          s += __shfl_xor(s, off);
          q += __shfl_xor(q, off);
        }
        if (lr == 0) {
          int rl = wm * 32 + m * 16 + hi * 4 + r;
          atomicAdd(&rsum[rl], s);
          atomicAdd(&rsq[rl], q);
        }
      }
    __syncthreads();
    #pragma unroll
    for (int m = 0; m < 2; m++)
      #pragma unroll
      for (int n = 0; n < 4; n++)
        #pragma unroll
        for (int r = 0; r < 4; r++) {
          int rl = wm * 32 + m * 16 + hi * 4 + r;
          int col = wn * 64 + n * 16 + lr;
          size_t gi = (size_t)(m0 + rl) * 256 + col;
          float mu = rsum[rl] * (1.f / 256.f);
          float var = rsq[rl] * (1.f / 256.f) - mu * mu;
          float rstd = rsqrtf(fmaxf(var, 0.f) + 1e-6f);
          C1[gi] = f2bf(g[col] * (acc[m][n][r] - mu) * rstd + be[col]);
        }
  }
}

// ---------------- wide s-vector projections (standalone, 256 thr) ----------
template <bool MEAN>
__global__ LCONST void proj_kernel(const float* __restrict__ X, const float* __restrict__ part,
                                   const float* __restrict__ Wq, const float* __restrict__ Wk,
                                   const float* __restrict__ Wv, float* __restrict__ Yq,
                                   float* __restrict__ Yk, float* __restrict__ Yv) {
  __shared__ float xs[256];
  __shared__ float red[256];
  const int b = blockIdx.x;
  const int wsel = blockIdx.y >> 2, n0 = (blockIdx.y & 3) * 64;
  const int tid = threadIdx.x;
  if constexpr (MEAN) {
    float s = 0.f;
    #pragma unroll
    for (int c = 0; c < 32; c++) s += part[((size_t)b * 32 + c) * 256 + tid];
    xs[tid] = s * (1.f / 2048.f);
  } else {
    xs[tid] = X[b * 256 + tid];
  }
  __syncthreads();
  const float* W = (wsel == 0) ? Wq : ((wsel == 1) ? Wk : Wv);
  float* Y = (wsel == 0) ? Yq : ((wsel == 1) ? Yk : Yv);
  const int c = tid & 63, g = tid >> 6;
  float p = 0.f;
  #pragma unroll 8
  for (int j = g * 64; j < g * 64 + 64; j++)
    p = fmaf(xs[j], W[(size_t)j * 256 + n0 + c], p);
  red[tid] = p;
  __syncthreads();
  if (g == 0)
    Y[b * 256 + n0 + c] = red[c] + red[64 + c] + red[128 + c] + red[192 + c];
}

// ---------------- M1: QKV1 GEMM (768 blk) || s0 projections (192 blk) ------
__global__ __launch_bounds__(512, 4)
void qkvproj_kernel(const u16* __restrict__ ebf, const u16* __restrict__ Wqkv_t,
                    u16* __restrict__ hq, u16* __restrict__ ek, u16* __restrict__ ev,
                    const float* __restrict__ part,
                    const float* __restrict__ Wq, const float* __restrict__ Wk,
                    const float* __restrict__ Wv, float* __restrict__ Yq,
                    float* __restrict__ Yk, float* __restrict__ Yv) {
  extern __shared__ __align__(16) char smem[];
  const int bid = blockIdx.x, tid = threadIdx.x;
  if (bid < 768) {
    u16* As = (u16*)smem;
    u16* Bs = As + 128 * 64;
    gemm_core<128, 256, 0>(bid, 768, As, Bs, ebf, Wqkv_t, nullptr,
                           hq, ek, ev, nullptr, nullptr, nullptr, nullptr, 768, 256);
  } else {
    float* xs = (float*)smem;
    float* red = xs + 256;
    const int vb = bid - 768;                  // 0..191
    const int b = vb & 15, y = vb >> 4;        // y: 0..11
    const int wsel = y >> 2, n0 = (y & 3) * 64;
    if (tid < 256) {
      float s = 0.f;
      #pragma unroll
      for (int c = 0; c < 32; c++) s += part[((size_t)b * 32 + c) * 256 + tid];
      xs[tid] = s * (1.f / 2048.f);
    }
    __syncthreads();
    const float* W = (wsel == 0) ? Wq : ((wsel == 1) ? Wk : Wv);
    float* Y = (wsel == 0) ? Yq : ((wsel == 1) ? Yk : Yv);
    const int c = tid & 63, g = tid >> 6;      // 8 groups of 32 j's
    float p = 0.f;
    #pragma unroll 8
    for (int j = g * 32; j < g * 32 + 32; j++)
      p = fmaf(xs[j], W[(size_t)j * 256 + n0 + c], p);
    red[tid] = p;
    __syncthreads();
    if (g == 0) {
      float v = 0.f;
      #pragma unroll
      for (int k = 0; k < 8; k++) v += red[k * 64 + c];
      Y[b * 256 + n0 + c] = v;
    }
  }
}

// ---------------- M2: FFN1 (1024 blk) || KV2 GEMM (512 blk) ----------------
__global__ __launch_bounds__(512, 4)
void kvffn_kernel(const u16* __restrict__ out1, const u16* __restrict__ W1_t,
                  const float* __restrict__ b1, u16* __restrict__ ffn1,
                  const u16* __restrict__ hbuf, const u16* __restrict__ Wkv_t,
                  u16* __restrict__ pk, u16* __restrict__ pv) {
  extern __shared__ __align__(16) char smem[];
  u16* As = (u16*)smem;
  u16* Bs = As + 128 * 64;
  const int bid = blockIdx.x;
  if (bid < 1024) {
    gemm_core<128, 256, 1>(bid, 1024, As, Bs, out1, W1_t, b1,
                           ffn1, nullptr, nullptr, nullptr, nullptr, nullptr, nullptr, 1024, 256);
  } else {
    gemm_core<128, 256, 0>(bid - 1024, 512, As, Bs, hbuf, Wkv_t, nullptr,
                           pk, pv, nullptr, nullptr, nullptr, nullptr, nullptr, 512, 256);
  }
}

// ---------------- MHA2 combine + s = relu(attn2@Wo+bo), wide ---------------
__global__ LCONST void mha2c_kernel(const float* __restrict__ partial,
                                    const float* __restrict__ Wo, const float* __restrict__ bo,
                                    float* __restrict__ Y) {
  __shared__ float xs[256];
  __shared__ float red[256];
  const int b = blockIdx.x;
  const int n0 = blockIdx.y * 64;
  const int tid = threadIdx.x;
  {
    int hh = tid >> 5, d = tid & 31;
    const float* P = partial + (size_t)(b * 8 + hh) * 144;
    float M = fmaxf(fmaxf(P[0], P[36]), fmaxf(P[72], P[108]));
    float l = 0.f, o = 0.f;
    #pragma unroll
    for (int c = 0; c < 4; c++) {
      float f = __expf(P[c * 36] - M);
      l += f * P[c * 36 + 1];
      o += f * P[c * 36 + 2 + d];
    }
    xs[tid] = o / l;
  }
  __syncthreads();
  const int c = tid & 63, g = tid >> 6;
  float p = 0.f;
  #pragma unroll 8
  for (int j = g * 64; j < g * 64 + 64; j++)
    p = fmaf(xs[j], Wo[(size_t)j * 256 + n0 + c], p);
  red[tid] = p;
  __syncthreads();
  if (g == 0) {
    float v = red[c] + red[64 + c] + red[128 + c] + red[192 + c];
    Y[b * 256 + n0 + c] = fmaxf(v + bo[n0 + c], 0.f);
  }
}

// ===========================================================================
extern "C" void kernel_launch(void* const* d_in, const int* in_sizes, int n_in,
                              void* d_out, int out_size, void* d_ws, size_t ws_size,
                              hipStream_t stream) {
  const float* e   = (const float*)d_in[0];
  const float* Wq  = (const float*)d_in[1];
  const float* Wk  = (const float*)d_in[2];
  const float* Wv  = (const float*)d_in[3];
  const float* Wo  = (const float*)d_in[4];
  const float* bo  = (const float*)d_in[5];
  const float* W1  = (const float*)d_in[6];
  const float* b1  = (const float*)d_in[7];
  const float* W2  = (const float*)d_in[8];
  const float* b2  = (const float*)d_in[9];
  const float* g1  = (const float*)d_in[10];
  const float* be1 = (const float*)d_in[11];
  const float* g2  = (const float*)d_in[12];
  const float* be2 = (const float*)d_in[13];

  char* wsb = (char*)d_ws;
  size_t off = 0;
  auto alc = [&](size_t n) { void* p = wsb + off; off += (n + 255) & ~(size_t)255; return p; };
  u16* Wqkv_t = (u16*)alc(768 * 256 * 2);     // rows 0-255 Wq, 256-511 Wk, 512-767 Wv
  u16* Wo_t   = (u16*)alc(65536 * 2);
  u16* W1_t   = (u16*)alc(262144 * 2);
  u16* W2_t   = (u16*)alc(262144 * 2);
  float* sB    = (float*)alc(4096 * 4);
  float* sqp   = (float*)alc(4096 * 4);
  float* skp   = (float*)alc(4096 * 4);
  float* svp   = (float*)alc(4096 * 4);
  float* partM = (float*)alc(512 * 36 * 4);
  float* part  = (float*)alc(524288);
  const size_t SZ = 16777216;                 // 32768*256*2 bytes
  // ffn1 (64 MB) overlays hq..ebf — ALL dead by the time kvffn writes it.
  // pk/pv/hbuf/out1 live past kvffn and sit OUTSIDE the overlay.
  u16* hq   = (u16*)alc(SZ);
  u16* ek   = (u16*)alc(SZ);
  u16* ev   = (u16*)alc(SZ);
  u16* ebf  = (u16*)alc(SZ);
  u16* pk   = (u16*)alc(SZ);
  u16* pv   = (u16*)alc(SZ);
  u16* hbuf = (u16*)alc(SZ);
  u16* out1 = (u16*)alc(SZ);
  u16* ffn1 = hq;                             // spans hq+ek+ev+ebf (64 MB)

  const int M = 32768;
  float* outp  = (float*)d_out;
  float* s_out = outp + 8388608;

  // ---- prep: weights -> bf16 transposed + partial mean + e->bf16 ----
  prep_kernel<<<3584, 256, 0, stream>>>(e, Wq, Wk, Wv, Wo, W1, W2,
      Wqkv_t, Wo_t, W1_t, W2_t, part, ebf);

  // ---------------- cycle 1 (h = e, s = s0) ----------------
  qkvproj_kernel<<<960, 512, 49152, stream>>>(ebf, Wqkv_t, hq, ek, ev,
      part, Wq, Wk, Wv, sqp, skp, svp);                   // QKV1 || s0-proj
  attnwo_kernel<1><<<512, 512, 0, stream>>>(hq, ek, ev, ek, ev, skp, svp,
      Wo_t, bo, hbuf, nullptr, nullptr, nullptr, nullptr);
  gemm3_kernel<128, 256, 0><<<768, 512, 0, stream>>>(hbuf, Wqkv_t, nullptr, hq, pk, pv,
      nullptr, nullptr, nullptr, nullptr, M, 768, 256);   // hq2, pk, pv
  mha2a_kernel<<<512, 256, 0, stream>>>(sqp, skp, svp, pk, pv, partM);
  mha2c_kernel<<<dim3(16, 4), 256, 0, stream>>>(partM, Wo, bo, sB);
  proj_kernel<false><<<dim3(16, 12), 256, 0, stream>>>(sB, nullptr, Wq, Wk, Wv, sqp, skp, svp);

  // ---------------- cycle 2 (h = h1, s = s1) ----------------
  attnwo_kernel<2><<<512, 512, 0, stream>>>(hq, pk, pv, ek, ev, skp, svp,
      Wo_t, bo, hbuf, out1, ebf, g1, be1);                // h2 + fused LN1
  kvffn_kernel<<<1536, 512, 49152, stream>>>(out1, W1_t, b1, ffn1,
      hbuf, Wqkv_t + 65536, pk, pv);                      // FFN1 || pk2,pv2
  mha2a_kernel<<<512, 256, 0, stream>>>(sqp, skp, svp, pk, pv, partM);
  mha2c_kernel<<<dim3(16, 4), 256, 0, stream>>>(partM, Wo, bo, s_out);  // s output
  gemm3_kernel<64, 256, 4><<<512, 512, 0, stream>>>(ffn1, W2_t, b2, nullptr, nullptr, nullptr,
      out1, g2, be2, outp, M, 256, 1024);                 // FFN2 + LN2
  (void)in_sizes; (void)n_in; (void)out_size; (void)ws_size;
}

// Round 15
// 258.121 us; speedup vs baseline: 1.3426x; 1.3426x over previous
//
#include <hip/hip_runtime.h>

typedef unsigned short u16;
typedef unsigned int u32;
typedef __attribute__((ext_vector_type(8))) short bf16x8;
typedef __attribute__((ext_vector_type(4))) float f32x4;

#define LCONST __launch_bounds__(256)

__device__ __forceinline__ u16 f2bf(float f) {
  u32 u = __float_as_uint(f);
  u32 r = (u + 0x7FFFu + ((u >> 16) & 1u)) >> 16;
  return (u16)r;
}
__device__ __forceinline__ float bflo(u32 w) { return __uint_as_float(w << 16); }
__device__ __forceinline__ float bfhi(u32 w) { return __uint_as_float(w & 0xFFFF0000u); }
__device__ __forceinline__ float b2f(u16 v) { return __uint_as_float(((u32)v) << 16); }

__device__ __forceinline__ float dot8(uint4 u, const float* q) {
  return q[0]*bflo(u.x) + q[1]*bfhi(u.x) + q[2]*bflo(u.y) + q[3]*bfhi(u.y)
       + q[4]*bflo(u.z) + q[5]*bfhi(u.z) + q[6]*bflo(u.w) + q[7]*bfhi(u.w);
}
__device__ __forceinline__ void fma8(uint4 u, float wt, float* a) {
  a[0] = fmaf(wt, bflo(u.x), a[0]); a[1] = fmaf(wt, bfhi(u.x), a[1]);
  a[2] = fmaf(wt, bflo(u.y), a[2]); a[3] = fmaf(wt, bfhi(u.y), a[3]);
  a[4] = fmaf(wt, bflo(u.z), a[4]); a[5] = fmaf(wt, bfhi(u.z), a[5]);
  a[6] = fmaf(wt, bflo(u.w), a[6]); a[7] = fmaf(wt, bfhi(u.w), a[7]);
}

// async global -> LDS, 16 bytes per lane. LDS dest = wave-uniform base + lane*16.
__device__ __forceinline__ void gload16(const u16* g, u16* l) {
  __builtin_amdgcn_global_load_lds(
      (const __attribute__((address_space(1))) unsigned int*)g,
      (__attribute__((address_space(3))) unsigned int*)l, 16, 0, 0);
}

// ---------------- prep: all weight transpose-casts + e-mean (one launch) ---
__global__ LCONST void prep_kernel(const float* __restrict__ e,
                                   const float* __restrict__ Wq, const float* __restrict__ Wk,
                                   const float* __restrict__ Wv, const float* __restrict__ Wo,
                                   const float* __restrict__ W1, const float* __restrict__ W2,
                                   u16* __restrict__ Wqkv_t, u16* __restrict__ Wo_t,
                                   u16* __restrict__ W1_t, u16* __restrict__ W2_t,
                                   float* __restrict__ part, u16* __restrict__ ebf) {
  int blk = blockIdx.x;
  int tid = threadIdx.x;
  if (blk < 3072) {                               // weight transpose-casts
    int idx = blk * 256 + tid;                    // 786432 total
    if (idx < 196608) {                           // Wq|Wk|Wv (256x256 each)
      int sub = idx >> 16, r = idx & 65535;
      int n = r >> 8, k = r & 255;
      const float* src = (sub == 0) ? Wq : ((sub == 1) ? Wk : Wv);
      Wqkv_t[idx] = f2bf(src[(size_t)k * 256 + n]);
    } else if (idx < 262144) {                    // Wo (256x256)
      int r = idx - 196608;
      int n = r >> 8, k = r & 255;
      Wo_t[r] = f2bf(Wo[(size_t)k * 256 + n]);
    } else if (idx < 524288) {                    // W1 (256x1024) -> [1024][256]
      int r = idx - 262144;
      int n = r >> 8, k = r & 255;
      W1_t[r] = f2bf(W1[(size_t)k * 1024 + n]);
    } else {                                      // W2 (1024x256) -> [256][1024]
      int r = idx - 524288;
      int n = r >> 10, k = r & 1023;
      W2_t[r] = f2bf(W2[(size_t)k * 256 + n]);
    }
  } else {                                        // partial mean + e->bf16
    int mb = blk - 3072;                          // 512 blocks
    int b = mb >> 5, c = mb & 31;
    size_t base = ((size_t)b * 2048 + (size_t)c * 64) * 256 + tid;
    float s = 0.f;
    #pragma unroll 8
    for (int i = 0; i < 64; i++) {
      float v = e[base + (size_t)i * 256];
      s += v;
      ebf[base + (size_t)i * 256] = f2bf(v);
    }
    part[(size_t)mb * 256 + tid] = s;
  }
}

// ---------------- MFMA GEMM: C = A(MxK,bf16) * Bt(NxK,bf16)^T --------------
// 512 threads, 2x4 waves. (BM,BN)=(128,256): wave 64x64, MR=4.
//                          (BM,BN)=(64,256):  wave 32x64, MR=2.
// EPI: 0 = plain bf16 store routed into 256-wide buffers C0/C1/C2 by col>>8
//      1 = relu(acc+bias) -> bf16 C0 (stride N)
//      4 = FFN2+LN2: x=acc+bias+resbf; LN(x) -> Fout (f32)
template <int BM, int BN, int EPI>
__global__ __launch_bounds__(512, (BM == 128) ? 4 : 6)
void gemm3_kernel(const u16* __restrict__ A, const u16* __restrict__ Bt,
                  const float* __restrict__ bias,
                  u16* __restrict__ C0, u16* __restrict__ C1, u16* __restrict__ C2,
                  const u16* __restrict__ resbf,
                  const float* __restrict__ g, const float* __restrict__ be,
                  float* __restrict__ Fout,
                  int M, int N, int K) {
  constexpr int WR = BM / 2;                 // rows per wave
  constexpr int MR = WR / 16;                // 4 or 2
  constexpr int ACH_PW = (BM / 8) / 8;       // A 1KB chunks per wave
  constexpr int BCH_PW = 4;                  // B 1KB chunks per wave
  __shared__ __align__(16) u16 As[BM * 64];
  __shared__ __align__(16) u16 Bs[BN * 64];

  const int tid = threadIdx.x, lane = tid & 63, wid = tid >> 6;
  const int wm = wid >> 2, wn = wid & 3;

  const int ncol = N / BN;
  const int nwg = gridDim.x;
  const int bid = blockIdx.x;
  const int swz = (bid & 7) * (nwg >> 3) + (bid >> 3);
  const int mb = swz / ncol, nb = swz - mb * ncol;
  const int m0 = mb * BM, n0 = nb * BN;

  const int lrow8 = lane >> 3;               // row within 8-row chunk
  const int cg = (lane & 7) ^ lrow8;         // pre-swizzled global 16B-slot

  f32x4 acc[MR][4] = {};
  for (int kt = 0; kt < K; kt += 64) {
    #pragma unroll
    for (int it = 0; it < ACH_PW; it++) {
      int ca = wid * ACH_PW + it;
      int row = ca * 8 + lrow8;
      gload16(A + (size_t)(m0 + row) * K + kt + cg * 8, (u16*)As + ca * 512);
    }
    #pragma unroll
    for (int it = 0; it < BCH_PW; it++) {
      int cb = wid * BCH_PW + it;
      int row = cb * 8 + lrow8;
      gload16(Bt + (size_t)(n0 + row) * K + kt + cg * 8, (u16*)Bs + cb * 512);
    }
    __syncthreads();
    const int lr = lane & 15, hi = lane >> 4;
    #pragma unroll
    for (int kk = 0; kk < 2; kk++) {
      const int slot = (kk * 4 + hi) ^ (lr & 7);
      bf16x8 af[MR], bfr[4];
      #pragma unroll
      for (int m = 0; m < MR; m++)
        af[m] = *(const bf16x8*)&As[(wm * WR + m * 16 + lr) * 64 + slot * 8];
      #pragma unroll
      for (int n = 0; n < 4; n++)
        bfr[n] = *(const bf16x8*)&Bs[(wn * 64 + n * 16 + lr) * 64 + slot * 8];
      #pragma unroll
      for (int m = 0; m < MR; m++)
        #pragma unroll
        for (int n = 0; n < 4; n++)
          acc[m][n] = __builtin_amdgcn_mfma_f32_16x16x32_bf16(af[m], bfr[n], acc[m][n], 0, 0, 0);
    }
    __syncthreads();
  }

  const int lr = lane & 15, hi = lane >> 4;
  if constexpr (EPI == 0) {
    const int bsel = n0 >> 8;
    u16* C = (bsel == 0) ? C0 : ((bsel == 1) ? C1 : C2);
    #pragma unroll
    for (int m = 0; m < MR; m++)
      #pragma unroll
      for (int n = 0; n < 4; n++)
        #pragma unroll
        for (int r = 0; r < 4; r++) {
          int row = m0 + wm * WR + m * 16 + hi * 4 + r;
          int col = wn * 64 + n * 16 + lr;
          C[(size_t)row * 256 + col] = f2bf(acc[m][n][r]);
        }
  } else if constexpr (EPI == 1) {
    #pragma unroll
    for (int m = 0; m < MR; m++)
      #pragma unroll
      for (int n = 0; n < 4; n++)
        #pragma unroll
        for (int r = 0; r < 4; r++) {
          int row = m0 + wm * WR + m * 16 + hi * 4 + r;
          int col = n0 + wn * 64 + n * 16 + lr;
          float v = fmaxf(acc[m][n][r] + bias[col], 0.f);
          C0[(size_t)row * N + col] = f2bf(v);
        }
  } else {  // EPI 4: FFN2 + LN2 epilogue
    __shared__ float rsum[BM], rsq[BM];
    if (tid < BM) { rsum[tid] = 0.f; rsq[tid] = 0.f; }
    __syncthreads();
    #pragma unroll
    for (int m = 0; m < MR; m++)
      #pragma unroll
      for (int n = 0; n < 4; n++)
        #pragma unroll
        for (int r = 0; r < 4; r++) {
          int rl = wm * WR + m * 16 + hi * 4 + r;
          int col = wn * 64 + n * 16 + lr;
          size_t gi = (size_t)(m0 + rl) * 256 + col;
          acc[m][n][r] = acc[m][n][r] + bias[col] + b2f(resbf[gi]);
        }
    #pragma unroll
    for (int m = 0; m < MR; m++)
      #pragma unroll
      for (int r = 0; r < 4; r++) {
        float s = 0.f, q = 0.f;
        #pragma unroll
        for (int n = 0; n < 4; n++) { float x = acc[m][n][r]; s += x; q += x * x; }
        #pragma unroll
        for (int off = 1; off < 16; off <<= 1) {
          s += __shfl_xor(s, off);
          q += __shfl_xor(q, off);
        }
        if (lr == 0) {
          int rl = wm * WR + m * 16 + hi * 4 + r;
          atomicAdd(&rsum[rl], s);
          atomicAdd(&rsq[rl], q);
        }
      }
    __syncthreads();
    #pragma unroll
    for (int m = 0; m < MR; m++)
      #pragma unroll
      for (int n = 0; n < 4; n++)
        #pragma unroll
        for (int r = 0; r < 4; r++) {
          int rl = wm * WR + m * 16 + hi * 4 + r;
          int col = wn * 64 + n * 16 + lr;
          size_t gi = (size_t)(m0 + rl) * 256 + col;
          float mu = rsum[rl] * (1.f / 256.f);
          float var = rsq[rl] * (1.f / 256.f) - mu * mu;
          float rstd = rsqrtf(fmaxf(var, 0.f) + 1e-6f);
          Fout[gi] = g[col] * (acc[m][n][r] - mu) * rstd + be[col];
        }
  }
}

// ---- fused attn1 + Wo GEMM: phase1 attention -> As(LDS), phase2 MFMA ------
// 512 blocks (M/64), 512 thr. Phase1: thread = (row r=tid>>3, head h=tid&7),
// writes 32 bf16 to As[64][256] with slot^row&7 swizzle. Phase2: B-staged
// GEMM, A read from persistent As.
// EPI 1: hbuf = relu(acc+bo) -> C0
// EPI 2: h2 = relu(acc+bo) -> C0; out1 = LN1(resbf + h2) -> C1
template <int EPI>
__global__ __launch_bounds__(512, 4)
void attnwo_kernel(const u16* __restrict__ hq, const u16* __restrict__ pk,
                   const u16* __restrict__ pv, const u16* __restrict__ ek,
                   const u16* __restrict__ ev, const float* __restrict__ skp,
                   const float* __restrict__ svp,
                   const u16* __restrict__ Wo_t, const float* __restrict__ bo,
                   u16* __restrict__ C0, u16* __restrict__ C1,
                   const u16* __restrict__ resbf,
                   const float* __restrict__ g, const float* __restrict__ be) {
  __shared__ __align__(16) u16 As[64 * 256];    // 32 KB, full-K A tile
  __shared__ __align__(16) u16 Bs[256 * 64];    // 32 KB, per-k-tile B
  const int tid = threadIdx.x, lane = tid & 63, wid = tid >> 6;
  const int wm = wid >> 2, wn = wid & 3;
  const int nwg = gridDim.x, bid = blockIdx.x;
  const int swz = (bid & 7) * (nwg >> 3) + (bid >> 3);
  const int m0 = swz * 64;

  // ---- phase 1: per-(row,head) 5-key attention ----
  {
    const int r = tid >> 3, h = tid & 7;
    const size_t token = (size_t)(m0 + r);
    const int b = (int)(token >> 11);
    const int i = (int)(token & 2047);
    const size_t tb = (size_t)b << 11;
    const size_t ip = tb + ((i + 1) & 2047);
    const size_t im = tb + ((i + 2047) & 2047);
    const int off = h * 32;

    float qf[32];
    {
      const u16* q = hq + token * 256 + off;
      #pragma unroll
      for (int c = 0; c < 4; c++) {
        uint4 u = *(const uint4*)(q + c * 8);
        qf[c*8+0] = bflo(u.x); qf[c*8+1] = bfhi(u.x);
        qf[c*8+2] = bflo(u.y); qf[c*8+3] = bfhi(u.y);
        qf[c*8+4] = bflo(u.z); qf[c*8+5] = bfhi(u.z);
        qf[c*8+6] = bflo(u.w); qf[c*8+7] = bfhi(u.w);
      }
    }
    const u16* kr0 = pk + ip * 256 + off;
    const u16* kr1 = pk + token * 256 + off;
    const u16* kr2 = pk + im * 256 + off;
    const u16* kr3 = ek + token * 256 + off;
    float lg[5];
    {
      float d0 = 0, d1 = 0, d2 = 0, d3 = 0;
      #pragma unroll
      for (int cc = 0; cc < 4; cc++) {
        d0 += dot8(*(const uint4*)(kr0 + cc * 8), qf + cc * 8);
        d1 += dot8(*(const uint4*)(kr1 + cc * 8), qf + cc * 8);
        d2 += dot8(*(const uint4*)(kr2 + cc * 8), qf + cc * 8);
        d3 += dot8(*(const uint4*)(kr3 + cc * 8), qf + cc * 8);
      }
      lg[0] = d0; lg[1] = d1; lg[2] = d2; lg[3] = d3;
      float d4 = 0;
      const float* s = skp + b * 256 + off;
      #pragma unroll
      for (int j = 0; j < 32; j++) d4 = fmaf(qf[j], s[j], d4);
      lg[4] = d4;
    }
    const float sc = 0.17677669529663687f;      // 1/sqrt(32)
    float mx = lg[0];
    #pragma unroll
    for (int c = 1; c < 5; c++) mx = fmaxf(mx, lg[c]);
    float w[5], den = 0.f;
    #pragma unroll
    for (int c = 0; c < 5; c++) { w[c] = __expf((lg[c] - mx) * sc); den += w[c]; }

    float a[32];
    #pragma unroll
    for (int j = 0; j < 32; j++) a[j] = 0.f;
    const u16* vr0 = pv + ip * 256 + off;
    const u16* vr1 = pv + token * 256 + off;
    const u16* vr2 = pv + im * 256 + off;
    const u16* vr3 = ev + token * 256 + off;
    #pragma unroll
    for (int cc = 0; cc < 4; cc++) {
      fma8(*(const uint4*)(vr0 + cc * 8), w[0], a + cc * 8);
      fma8(*(const uint4*)(vr1 + cc * 8), w[1], a + cc * 8);
      fma8(*(const uint4*)(vr2 + cc * 8), w[2], a + cc * 8);
      fma8(*(const uint4*)(vr3 + cc * 8), w[3], a + cc * 8);
    }
    {
      const float* s = svp + b * 256 + off;
      #pragma unroll
      for (int j = 0; j < 32; j++) a[j] = fmaf(w[4], s[j], a[j]);
    }
    const float inv = 1.f / den;
    #pragma unroll
    for (int c = 0; c < 4; c++) {
      uint4 u;
      u.x = (u32)f2bf(a[c*8+0] * inv) | ((u32)f2bf(a[c*8+1] * inv) << 16);
      u.y = (u32)f2bf(a[c*8+2] * inv) | ((u32)f2bf(a[c*8+3] * inv) << 16);
      u.z = (u32)f2bf(a[c*8+4] * inv) | ((u32)f2bf(a[c*8+5] * inv) << 16);
      u.w = (u32)f2bf(a[c*8+6] * inv) | ((u32)f2bf(a[c*8+7] * inv) << 16);
      int s = h * 4 + c;
      int sp = (s & 24) | ((s & 7) ^ (r & 7));
      *(uint4*)&As[r * 256 + sp * 8] = u;
    }
  }
  __syncthreads();

  // ---- phase 2: C = As @ Wo_t^T (B staged per k-tile; A persistent) ----
  const int lrow8 = lane >> 3;
  const int cg = (lane & 7) ^ lrow8;
  const int lr = lane & 15, hi = lane >> 4;
  f32x4 acc[2][4] = {};
  for (int kt = 0; kt < 4; kt++) {
    #pragma unroll
    for (int it = 0; it < 4; it++) {
      int cb = wid * 4 + it;
      int row = cb * 8 + lrow8;
      gload16(Wo_t + (size_t)row * 256 + kt * 64 + cg * 8, (u16*)Bs + cb * 512);
    }
    __syncthreads();
    #pragma unroll
    for (int kk = 0; kk < 2; kk++) {
      bf16x8 af[2], bfr[4];
      #pragma unroll
      for (int m = 0; m < 2; m++) {
        int row = wm * 32 + m * 16 + lr;
        int sp = kt * 8 + ((kk * 4 + hi) ^ (row & 7));
        af[m] = *(const bf16x8*)&As[row * 256 + sp * 8];
      }
      const int slotB = (kk * 4 + hi) ^ (lr & 7);
      #pragma unroll
      for (int n = 0; n < 4; n++)
        bfr[n] = *(const bf16x8*)&Bs[(wn * 64 + n * 16 + lr) * 64 + slotB * 8];
      #pragma unroll
      for (int m = 0; m < 2; m++)
        #pragma unroll
        for (int n = 0; n < 4; n++)
          acc[m][n] = __builtin_amdgcn_mfma_f32_16x16x32_bf16(af[m], bfr[n], acc[m][n], 0, 0, 0);
    }
    __syncthreads();
  }

  if constexpr (EPI == 1) {
    #pragma unroll
    for (int m = 0; m < 2; m++)
      #pragma unroll
      for (int n = 0; n < 4; n++)
        #pragma unroll
        for (int r = 0; r < 4; r++) {
          int row = m0 + wm * 32 + m * 16 + hi * 4 + r;
          int col = wn * 64 + n * 16 + lr;
          float v = fmaxf(acc[m][n][r] + bo[col], 0.f);
          C0[(size_t)row * 256 + col] = f2bf(v);
        }
  } else {  // EPI 2: h2 + fused LN1
    __shared__ float rsum[64], rsq[64];
    if (tid < 64) { rsum[tid] = 0.f; rsq[tid] = 0.f; }
    __syncthreads();
    #pragma unroll
    for (int m = 0; m < 2; m++)
      #pragma unroll
      for (int n = 0; n < 4; n++)
        #pragma unroll
        for (int r = 0; r < 4; r++) {
          int rl = wm * 32 + m * 16 + hi * 4 + r;
          int col = wn * 64 + n * 16 + lr;
          size_t gi = (size_t)(m0 + rl) * 256 + col;
          float v = fmaxf(acc[m][n][r] + bo[col], 0.f);
          C0[gi] = f2bf(v);              // h2
          acc[m][n][r] = b2f(resbf[gi]) + v;   // e + h
        }
    #pragma unroll
    for (int m = 0; m < 2; m++)
      #pragma unroll
      for (int r = 0; r < 4; r++) {
        float s = 0.f, q = 0.f;
        #pragma unroll
        for (int n = 0; n < 4; n++) { float x = acc[m][n][r]; s += x; q += x * x; }
        #pragma unroll
        for (int off = 1; off < 16; off <<= 1) {
          s += __shfl_xor(s, off);
          q += __shfl_xor(q, off);
        }
        if (lr == 0) {
          int rl = wm * 32 + m * 16 + hi * 4 + r;
          atomicAdd(&rsum[rl], s);
          atomicAdd(&rsq[rl], q);
        }
      }
    __syncthreads();
    #pragma unroll
    for (int m = 0; m < 2; m++)
      #pragma unroll
      for (int n = 0; n < 4; n++)
        #pragma unroll
        for (int r = 0; r < 4; r++) {
          int rl = wm * 32 + m * 16 + hi * 4 + r;
          int col = wn * 64 + n * 16 + lr;
          size_t gi = (size_t)(m0 + rl) * 256 + col;
          float mu = rsum[rl] * (1.f / 256.f);
          float var = rsq[rl] * (1.f / 256.f) - mu * mu;
          float rstd = rsqrtf(fmaxf(var, 0.f) + 1e-6f);
          C1[gi] = f2bf(g[col] * (acc[m][n][r] - mu) * rstd + be[col]);
        }
  }
}

// ---------------- wide s-vector projections: Yq/Yk/Yv = X @ W --------------
template <bool MEAN>
__global__ LCONST void proj_kernel(const float* __restrict__ X, const float* __restrict__ part,
                                   const float* __restrict__ Wq, const float* __restrict__ Wk,
                                   const float* __restrict__ Wv, float* __restrict__ Yq,
                                   float* __restrict__ Yk, float* __restrict__ Yv) {
  __shared__ float xs[256];
  __shared__ float red[256];
  const int b = blockIdx.x;
  const int wsel = blockIdx.y >> 2, n0 = (blockIdx.y & 3) * 64;
  const int tid = threadIdx.x;
  if constexpr (MEAN) {
    float s = 0.f;
    #pragma unroll
    for (int c = 0; c < 32; c++) s += part[((size_t)b * 32 + c) * 256 + tid];
    xs[tid] = s * (1.f / 2048.f);
  } else {
    xs[tid] = X[b * 256 + tid];
  }
  __syncthreads();
  const float* W = (wsel == 0) ? Wq : ((wsel == 1) ? Wk : Wv);
  float* Y = (wsel == 0) ? Yq : ((wsel == 1) ? Yk : Yv);
  const int c = tid & 63, g = tid >> 6;
  float p = 0.f;
  #pragma unroll 8
  for (int j = g * 64; j < g * 64 + 64; j++)
    p = fmaf(xs[j], W[(size_t)j * 256 + n0 + c], p);
  red[tid] = p;
  __syncthreads();
  if (g == 0)
    Y[b * 256 + n0 + c] = red[c] + red[64 + c] + red[128 + c] + red[192 + c];
}

// ---------------- MHA2 split: 4 key-chunks per (b,h) -----------------------
__global__ LCONST void mha2a_kernel(const float* __restrict__ sqp, const float* __restrict__ skp,
                                    const float* __restrict__ svp, const u16* __restrict__ pk,
                                    const u16* __restrict__ pv, float* __restrict__ partial) {
  __shared__ float rmax[4], rsum[4], racc[4][32];
  const int blk = blockIdx.x;                 // bh*4 + c
  const int bh = blk >> 2, c = blk & 3;
  const int b = bh >> 3, h = bh & 7;
  const int tid = threadIdx.x;
  const int lane = tid & 63, wid = tid >> 6;
  const int off = h * 32;
  const float sc = 0.17677669529663687f;

  float qf[32];
  {
    const float* q = sqp + b * 256 + off;
    #pragma unroll
    for (int j = 0; j < 32; j++) qf[j] = q[j];
  }
  const int k0 = c * 512 + tid;               // two h-keys per thread
  const int k1 = k0 + 256;
  const u16* kp0 = pk + ((size_t)b * 2048 + k0) * 256 + off;
  const u16* kp1 = pk + ((size_t)b * 2048 + k1) * 256 + off;
  float d0 = 0.f, d1 = 0.f;
  #pragma unroll
  for (int cc = 0; cc < 4; cc++) {
    d0 += dot8(*(const uint4*)(kp0 + cc * 8), qf + cc * 8);
    d1 += dot8(*(const uint4*)(kp1 + cc * 8), qf + cc * 8);
  }
  d0 *= sc; d1 *= sc;
  float ds = -1e30f;
  if (c == 0 && tid == 0) {                   // the s-key
    float d = 0.f;
    const float* k = skp + b * 256 + off;
    #pragma unroll
    for (int j = 0; j < 32; j++) d = fmaf(qf[j], k[j], d);
    ds = d * sc;
  }
  float lmax = fmaxf(fmaxf(d0, d1), ds);
  #pragma unroll
  for (int o = 32; o; o >>= 1) lmax = fmaxf(lmax, __shfl_down(lmax, o));
  if (lane == 0) rmax[wid] = lmax;
  __syncthreads();
  const float M = fmaxf(fmaxf(rmax[0], rmax[1]), fmaxf(rmax[2], rmax[3]));

  float w0 = __expf(d0 - M), w1 = __expf(d1 - M);
  float lsum = w0 + w1;
  float a[32];
  #pragma unroll
  for (int j = 0; j < 32; j++) a[j] = 0.f;
  const u16* vp0 = pv + ((size_t)b * 2048 + k0) * 256 + off;
  const u16* vp1 = pv + ((size_t)b * 2048 + k1) * 256 + off;
  #pragma unroll
  for (int cc = 0; cc < 4; cc++) {
    fma8(*(const uint4*)(vp0 + cc * 8), w0, a + cc * 8);
    fma8(*(const uint4*)(vp1 + cc * 8), w1, a + cc * 8);
  }
  if (c == 0 && tid == 0) {
    float ws = __expf(ds - M);
    lsum += ws;
    const float* v = svp + b * 256 + off;
    #pragma unroll
    for (int j = 0; j < 32; j++) a[j] = fmaf(ws, v[j], a[j]);
  }
  #pragma unroll
  for (int o = 32; o; o >>= 1) lsum += __shfl_down(lsum, o);
  if (lane == 0) rsum[wid] = lsum;
  #pragma unroll
  for (int j = 0; j < 32; j++) {
    float v = a[j];
    #pragma unroll
    for (int o = 32; o; o >>= 1) v += __shfl_down(v, o);
    if (lane == 0) racc[wid][j] = v;
  }
  __syncthreads();
  float* P = partial + (size_t)blk * 36;
  if (tid < 32) {
    P[2 + tid] = racc[0][tid] + racc[1][tid] + racc[2][tid] + racc[3][tid];
    if (tid == 0) {
      P[0] = M;
      P[1] = rsum[0] + rsum[1] + rsum[2] + rsum[3];
    }
  }
}

// ---------------- MHA2 combine + s = relu(attn2@Wo+bo), wide ---------------
__global__ LCONST void mha2c_kernel(const float* __restrict__ partial,
                                    const float* __restrict__ Wo, const float* __restrict__ bo,
                                    float* __restrict__ Y) {
  __shared__ float xs[256];
  __shared__ float red[256];
  const int b = blockIdx.x;
  const int n0 = blockIdx.y * 64;
  const int tid = threadIdx.x;
  {
    int hh = tid >> 5, d = tid & 31;
    const float* P = partial + (size_t)(b * 8 + hh) * 144;
    float M = fmaxf(fmaxf(P[0], P[36]), fmaxf(P[72], P[108]));
    float l = 0.f, o = 0.f;
    #pragma unroll
    for (int c = 0; c < 4; c++) {
      float f = __expf(P[c * 36] - M);
      l += f * P[c * 36 + 1];
      o += f * P[c * 36 + 2 + d];
    }
    xs[tid] = o / l;
  }
  __syncthreads();
  const int c = tid & 63, g = tid >> 6;
  float p = 0.f;
  #pragma unroll 8
  for (int j = g * 64; j < g * 64 + 64; j++)
    p = fmaf(xs[j], Wo[(size_t)j * 256 + n0 + c], p);
  red[tid] = p;
  __syncthreads();
  if (g == 0) {
    float v = red[c] + red[64 + c] + red[128 + c] + red[192 + c];
    Y[b * 256 + n0 + c] = fmaxf(v + bo[n0 + c], 0.f);
  }
}

// ===========================================================================
extern "C" void kernel_launch(void* const* d_in, const int* in_sizes, int n_in,
                              void* d_out, int out_size, void* d_ws, size_t ws_size,
                              hipStream_t stream) {
  const float* e   = (const float*)d_in[0];
  const float* Wq  = (const float*)d_in[1];
  const float* Wk  = (const float*)d_in[2];
  const float* Wv  = (const float*)d_in[3];
  const float* Wo  = (const float*)d_in[4];
  const float* bo  = (const float*)d_in[5];
  const float* W1  = (const float*)d_in[6];
  const float* b1  = (const float*)d_in[7];
  const float* W2  = (const float*)d_in[8];
  const float* b2  = (const float*)d_in[9];
  const float* g1  = (const float*)d_in[10];
  const float* be1 = (const float*)d_in[11];
  const float* g2  = (const float*)d_in[12];
  const float* be2 = (const float*)d_in[13];

  char* wsb = (char*)d_ws;
  size_t off = 0;
  auto alc = [&](size_t n) { void* p = wsb + off; off += (n + 255) & ~(size_t)255; return p; };
  u16* Wqkv_t = (u16*)alc(768 * 256 * 2);     // rows 0-255 Wq, 256-511 Wk, 512-767 Wv
  u16* Wo_t   = (u16*)alc(65536 * 2);
  u16* W1_t   = (u16*)alc(262144 * 2);
  u16* W2_t   = (u16*)alc(262144 * 2);
  float* sB    = (float*)alc(4096 * 4);
  float* sqp   = (float*)alc(4096 * 4);
  float* skp   = (float*)alc(4096 * 4);
  float* svp   = (float*)alc(4096 * 4);
  float* partM = (float*)alc(512 * 36 * 4);
  float* part  = (float*)alc(524288);
  const size_t SZ = 16777216;                 // 32768*256*2 bytes
  u16* hq   = (u16*)alc(SZ);                  // ffn1 aliases hq (64 MB region)
  u16* ek   = (u16*)alc(SZ);
  u16* ev   = (u16*)alc(SZ);
  u16* pk   = (u16*)alc(SZ);
  u16* pv   = (u16*)alc(SZ);
  u16* hbuf = (u16*)alc(SZ);
  u16* ebf  = (u16*)alc(SZ);
  u16* out1 = (u16*)alc(SZ);
  u16* ffn1 = hq;

  const int M = 32768;
  float* outp  = (float*)d_out;
  float* s_out = outp + 8388608;

  // ---- prep: weights -> bf16 transposed + partial mean + e->bf16 ----
  prep_kernel<<<3584, 256, 0, stream>>>(e, Wq, Wk, Wv, Wo, W1, W2,
      Wqkv_t, Wo_t, W1_t, W2_t, part, ebf);

  // ---------------- cycle 1 (h = e, s = s0) ----------------
  proj_kernel<true><<<dim3(16, 12), 256, 0, stream>>>(nullptr, part, Wq, Wk, Wv, sqp, skp, svp);
  gemm3_kernel<128, 256, 0><<<768, 512, 0, stream>>>(ebf, Wqkv_t, nullptr, hq, ek, ev,
      nullptr, nullptr, nullptr, nullptr, M, 768, 256);
  attnwo_kernel<1><<<512, 512, 0, stream>>>(hq, ek, ev, ek, ev, skp, svp,
      Wo_t, bo, hbuf, nullptr, nullptr, nullptr, nullptr);
  gemm3_kernel<128, 256, 0><<<768, 512, 0, stream>>>(hbuf, Wqkv_t, nullptr, hq, pk, pv,
      nullptr, nullptr, nullptr, nullptr, M, 768, 256);   // hq2, pk, pv
  mha2a_kernel<<<512, 256, 0, stream>>>(sqp, skp, svp, pk, pv, partM);
  mha2c_kernel<<<dim3(16, 4), 256, 0, stream>>>(partM, Wo, bo, sB);
  proj_kernel<false><<<dim3(16, 12), 256, 0, stream>>>(sB, nullptr, Wq, Wk, Wv, sqp, skp, svp);

  // ---------------- cycle 2 (h = h1, s = s1) ----------------
  attnwo_kernel<2><<<512, 512, 0, stream>>>(hq, pk, pv, ek, ev, skp, svp,
      Wo_t, bo, hbuf, out1, ebf, g1, be1);                // h2 + fused LN1
  gemm3_kernel<128, 256, 0><<<512, 512, 0, stream>>>(hbuf, Wqkv_t + 65536, nullptr, pk, pv, nullptr,
      nullptr, nullptr, nullptr, nullptr, M, 512, 256);   // pk2, pv2
  mha2a_kernel<<<512, 256, 0, stream>>>(sqp, skp, svp, pk, pv, partM);
  mha2c_kernel<<<dim3(16, 4), 256, 0, stream>>>(partM, Wo, bo, s_out);  // s output

  // ---------------- epilogue: FFN (LN2 fused into FFN2) ----------------
  gemm3_kernel<128, 256, 1><<<1024, 512, 0, stream>>>(out1, W1_t, b1, ffn1, nullptr, nullptr,
      nullptr, nullptr, nullptr, nullptr, M, 1024, 256);
  gemm3_kernel<64, 256, 4><<<512, 512, 0, stream>>>(ffn1, W2_t, b2, nullptr, nullptr, nullptr,
      out1, g2, be2, outp, M, 256, 1024);
  (void)in_sizes; (void)n_in; (void)out_size; (void)ws_size;
}